// Round 19
// baseline (134.257 us; speedup 1.0000x reference)
//
#include <hip/hip_runtime.h>
#include <math.h>

#define B_ 4
#define T_ 2048
#define C_ 768
#define H_ 12
#define D_ 64
#define N3C (3*C_)
#define BH_ (B_*H_)
#define QSCALE 11.5415603f   // 8 * log2(e): fold sqrt(d) and exp->exp2 into Q

typedef float f32x4 __attribute__((ext_vector_type(4)));
typedef _Float16 f16x8 __attribute__((ext_vector_type(8)));
typedef _Float16 f16x4v __attribute__((ext_vector_type(4)));
typedef unsigned short ushort_t;

__device__ __forceinline__ void async16(const void* g, void* l) {
    __builtin_amdgcn_global_load_lds(
        (const __attribute__((address_space(1))) unsigned int*)(g),
        (__attribute__((address_space(3))) unsigned int*)(l),
        16, 0, 0);
}

__device__ __forceinline__ unsigned pk_f16(float a, float b) {
    __fp16 r2[2];
    *(__fp16 __attribute__((ext_vector_type(2)))*)r2 = __builtin_amdgcn_cvt_pkrtz(a, b);
    return *(unsigned*)r2;
}

// ---------------- Kernel 0: fused Xh = fp16(x) + Wh[n][k] = fp16(W[k][n]) ----------------
__global__ __launch_bounds__(256) void conv_xw(const float* __restrict__ x,
                                               const float* __restrict__ W,
                                               _Float16* __restrict__ Xh,
                                               _Float16* __restrict__ Wh)
{
    __shared__ float tile[64][65];
    int bid = blockIdx.x;
    int tid = threadIdx.x;
    if (bid < 3072) {                                // x conversion: 8192*768/8 octs
        int idx = bid * 256 + tid;
        const float4 a = *reinterpret_cast<const float4*>(&x[(size_t)idx * 8]);
        const float4 b = *reinterpret_cast<const float4*>(&x[(size_t)idx * 8 + 4]);
        f16x8 o = {(_Float16)a.x, (_Float16)a.y, (_Float16)a.z, (_Float16)a.w,
                   (_Float16)b.x, (_Float16)b.y, (_Float16)b.z, (_Float16)b.w};
        *reinterpret_cast<f16x8*>(&Xh[(size_t)idx * 8]) = o;
    } else {                                         // W transpose+convert
        int b2 = bid - 3072;
        int n0 = (b2 % 36) * 64, k0 = (b2 / 36) * 64;
        #pragma unroll
        for (int t = 0; t < 16; ++t) {
            int c = t * 256 + tid;
            int kr = c >> 6, nc = c & 63;
            tile[kr][nc] = W[(size_t)(k0 + kr) * N3C + n0 + nc];
        }
        __syncthreads();
        #pragma unroll
        for (int t = 0; t < 16; ++t) {
            int c = t * 256 + tid;
            int nr = c >> 6, kc = c & 63;
            Wh[(size_t)(n0 + nr) * C_ + k0 + kc] = (_Float16)tile[kc][nr];
        }
    }
}

// ---------------- Kernel 1: qkv GEMM, fp16 MFMA, K=768 (2-phase dbuf, R15) ----------------
__global__ __launch_bounds__(256) void qkv_gemm(const _Float16* __restrict__ Xh,
                                                const _Float16* __restrict__ Wh,
                                                const float* __restrict__ bias,
                                                _Float16* __restrict__ Qf,
                                                _Float16* __restrict__ Kf,
                                                _Float16* __restrict__ Vt)
{
    __shared__ __align__(16) ushort_t SMEM[2 * 2 * 128 * 64];   // 64 KB

    int tid = threadIdx.x, lane = tid & 63, w = tid >> 6;
    int wm = w >> 1, wn = w & 1;
    int l15 = lane & 15, l4 = lane >> 4;
    int srow = lane >> 3;
    int scol = (((lane & 7) ^ srow)) << 3;

    int wg = blockIdx.x;
    int l = (wg & 7) * 144 + (wg >> 3);
    int mt = l / 18, nt = l % 18;
    int row0 = mt * 128, col0 = nt * 128;

    f32x4 acc[4][4];
    #pragma unroll
    for (int i = 0; i < 4; ++i)
        #pragma unroll
        for (int j = 0; j < 4; ++j)
            acc[i][j] = f32x4{0.f, 0.f, 0.f, 0.f};

    #pragma unroll
    for (int j = 0; j < 4; ++j) {
        int rowb = w * 32 + j * 8;
        async16(Xh + (size_t)(row0 + rowb + srow) * C_ + scol, &SMEM[rowb * 64]);
        async16(Wh + (size_t)(col0 + rowb + srow) * C_ + scol, &SMEM[8192 + rowb * 64]);
    }
    __syncthreads();

    int cur = 0;
    for (int it = 0; it < 12; ++it) {
        int nxt = cur ^ 1;
        int k0n = (it + 1) * 64;
        bool pf = (it + 1 < 12);
        const char* AsC = (const char*)(SMEM + cur * 16384);
        const char* BsC = AsC + 16384;
        ushort_t* An = SMEM + nxt * 16384;
        ushort_t* Bn = An + 8192;

        if (pf) {
            #pragma unroll
            for (int j = 0; j < 2; ++j) {
                int rowb = w * 32 + j * 8;
                async16(Xh + (size_t)(row0 + rowb + srow) * C_ + k0n + scol, &An[rowb * 64]);
                async16(Wh + (size_t)(col0 + rowb + srow) * C_ + k0n + scol, &Bn[rowb * 64]);
            }
        }
        f16x8 bfr[4][2];
        #pragma unroll
        for (int n = 0; n < 4; ++n) {
            int r = wn * 64 + n * 16 + l15;
            #pragma unroll
            for (int kk = 0; kk < 2; ++kk)
                bfr[n][kk] = *reinterpret_cast<const f16x8*>(BsC + r * 128 + ((kk * 64 + l4 * 16) ^ ((r & 7) << 4)));
        }
        {
            f16x8 af[2][2];
            #pragma unroll
            for (int m = 0; m < 2; ++m) {
                int r = wm * 64 + m * 16 + l15;
                #pragma unroll
                for (int kk = 0; kk < 2; ++kk)
                    af[m][kk] = *reinterpret_cast<const f16x8*>(AsC + r * 128 + ((kk * 64 + l4 * 16) ^ ((r & 7) << 4)));
            }
            #pragma unroll
            for (int kk = 0; kk < 2; ++kk)
                #pragma unroll
                for (int m = 0; m < 2; ++m)
                    #pragma unroll
                    for (int n = 0; n < 4; ++n)
                        acc[m][n] = __builtin_amdgcn_mfma_f32_16x16x32_f16(af[m][kk], bfr[n][kk], acc[m][n], 0, 0, 0);
        }

        if (pf) {
            #pragma unroll
            for (int j = 2; j < 4; ++j) {
                int rowb = w * 32 + j * 8;
                async16(Xh + (size_t)(row0 + rowb + srow) * C_ + k0n + scol, &An[rowb * 64]);
                async16(Wh + (size_t)(col0 + rowb + srow) * C_ + k0n + scol, &Bn[rowb * 64]);
            }
        }
        {
            f16x8 af[2][2];
            #pragma unroll
            for (int m = 0; m < 2; ++m) {
                int r = wm * 64 + (m + 2) * 16 + l15;
                #pragma unroll
                for (int kk = 0; kk < 2; ++kk)
                    af[m][kk] = *reinterpret_cast<const f16x8*>(AsC + r * 128 + ((kk * 64 + l4 * 16) ^ ((r & 7) << 4)));
            }
            #pragma unroll
            for (int kk = 0; kk < 2; ++kk)
                #pragma unroll
                for (int m = 0; m < 2; ++m)
                    #pragma unroll
                    for (int n = 0; n < 4; ++n)
                        acc[m + 2][n] = __builtin_amdgcn_mfma_f32_16x16x32_f16(af[m][kk], bfr[n][kk], acc[m + 2][n], 0, 0, 0);
        }

        __syncthreads();
        cur = nxt;
    }

    // epilogue: stage fp16 tile in LDS, coalesced 16B stores
    char* EB = (char*)SMEM;
    int p = col0 / C_;

    if (p < 2) {
        #pragma unroll
        for (int n = 0; n < 4; ++n) {
            int col = wn * 64 + n * 16 + l15;
            float bv = bias[col0 + col];
            #pragma unroll
            for (int m = 0; m < 4; ++m) {
                #pragma unroll
                for (int r = 0; r < 4; ++r) {
                    int row = wm * 64 + m * 16 + l4 * 4 + r;
                    float v = acc[m][n][r] + bv;
                    if (p == 0) v *= QSCALE;
                    int off = row * 256 + ((col * 2) ^ ((row & 7) << 4));
                    *reinterpret_cast<_Float16*>(EB + off) = (_Float16)v;
                }
            }
        }
        __syncthreads();
        int ti = tid >> 1, half = tid & 1;
        int grow = row0 + ti;
        int bq = grow >> 11, t = grow & (T_ - 1);
        int rem = (col0 + half * 64) - p * C_;
        int hh = rem >> 6;
        _Float16* dst = (p == 0 ? Qf : Kf) + ((size_t)(bq * H_ + hh) * T_ + t) * D_;
        #pragma unroll
        for (int u = 0; u < 8; ++u) {
            int off = ti * 256 + ((half * 128 + u * 16) ^ ((ti & 7) << 4));
            *reinterpret_cast<uint4*>((char*)dst + u * 16) = *reinterpret_cast<const uint4*>(EB + off);
        }
    } else {
        #pragma unroll
        for (int n = 0; n < 4; ++n) {
            int col = wn * 64 + n * 16 + l15;
            float bv = bias[col0 + col];
            #pragma unroll
            for (int m = 0; m < 4; ++m) {
                int row = wm * 64 + m * 16 + l4 * 4;
                uint2 pk;
                pk.x = pk_f16(acc[m][n][0] + bv, acc[m][n][1] + bv);
                pk.y = pk_f16(acc[m][n][2] + bv, acc[m][n][3] + bv);
                int off = col * 256 + ((row * 2) ^ ((col & 15) << 4));
                *reinterpret_cast<uint2*>(EB + off) = pk;
            }
        }
        __syncthreads();
        int dcol = tid >> 1, half = tid & 1;
        int rem = (col0 + dcol) - 1536;
        int hh = rem >> 6, dd = rem & 63;
        int bq = row0 >> 11, t0 = row0 & (T_ - 1);
        _Float16* dst = Vt + ((size_t)(bq * H_ + hh) * D_ + dd) * T_ + t0 + half * 64;
        #pragma unroll
        for (int u = 0; u < 8; ++u) {
            int off = dcol * 256 + ((half * 128 + u * 16) ^ ((dcol & 15) << 4));
            *reinterpret_cast<uint4*>((char*)dst + u * 16) = *reinterpret_cast<const uint4*>(EB + off);
        }
    }
}

// ---------------- Kernel 2: flash attention (R16/R18 inner loop, <=8-tile chunks) ---------
// Work item = (bh, qt, chunk): qt<4 single; qt 4-7 -> 2 chunks; 8-11 -> 3; 12-15 -> 4.
// Chunk c of nc covers tiles [c*nt/nc, (c+1)*nt/nc); all chunks <= 8 tiles (quantum halved
// vs R18). 40 items/bh = 1920 blocks (7.5/CU), rank-ordered longest-first.
__device__ const unsigned char ITEM_QT[40] = {
    15,15,15,15,14,14,11,11,11,10, 7, 7, 3,     // len 8
    14,14,13,13,13,13,12,12,10,10, 9, 9, 6, 6,  // len 7
    12,12, 9, 8, 8, 8, 5, 5, 2,                 // len 6
     4, 4, 1, 0};                               // len 5,5,4,2
__device__ const unsigned char ITEM_CH[40] = {
     0, 1, 2, 3, 1, 3, 0, 1, 2, 2, 0, 1, 0,
     0, 2, 0, 1, 2, 3, 1, 3, 0, 1, 1, 2, 0, 1,
     0, 2, 0, 0, 1, 2, 0, 1, 0,
     0, 1, 0, 0};

__global__ __launch_bounds__(256, 4) void attn(const _Float16* __restrict__ Qf,
                                               const _Float16* __restrict__ Kf,
                                               const _Float16* __restrict__ Vt,
                                               float* __restrict__ out,
                                               ushort_t* __restrict__ Oph,
                                               float* __restrict__ ML)
{
    // shorts layout: buf0 K[4096] V[4096] | buf1 K V  = 32768 B
    __shared__ __align__(16) char smem[32768];
    ushort_t* lds = (ushort_t*)smem;

    int tid = threadIdx.x, lane = tid & 63, w = tid >> 6;
    int l15 = lane & 15, l4 = lane >> 4;
    int bid = blockIdx.x;
    int rank = bid / BH_;
    int bh = bid % BH_;
    int qt = ITEM_QT[rank];
    int ch = ITEM_CH[rank];
    int b = bh / H_, h = bh % H_;
    int q0 = qt * 128;

    int ntl = 2 * qt + 2;
    int nc  = (qt >= 4) ? ((2 * qt + 9) >> 3) : 1;   // 2,3,4 chunks
    int it0 = ch * ntl / nc;
    int it1 = (ch + 1) * ntl / nc;

    f16x8 qf[2][2];
    #pragma unroll
    for (int qs = 0; qs < 2; ++qs) {
        int q = q0 + w * 32 + qs * 16 + l15;
        const _Float16* ph = Qf + ((size_t)bh * T_ + q) * D_;
        qf[qs][0] = *reinterpret_cast<const f16x8*>(ph + l4 * 8);
        qf[qs][1] = *reinterpret_cast<const f16x8*>(ph + 32 + l4 * 8);
    }

    f32x4 yacc[2][4];
    #pragma unroll
    for (int qs = 0; qs < 2; ++qs)
        #pragma unroll
        for (int dt = 0; dt < 4; ++dt)
            yacc[qs][dt] = f32x4{0.f, 0.f, 0.f, 0.f};
    float m_run[2] = {-INFINITY, -INFINITY};
    float l_run[2] = {0.f, 0.f};          // per-lane PARTIAL (reduced at epilogue)

    int srow = lane >> 3;
    int scol = ((lane & 7) ^ srow) << 3;

    const _Float16* kp[2];
    const _Float16* vp[2];
    #pragma unroll
    for (int j = 0; j < 2; ++j) {
        int ldsrow = (w * 2 + j) * 8 + srow;
        // kappa: LDS row -> global key offset (bijective on [0,64))
        int kperm = ((ldsrow >> 4) & 1) * 32 + ((ldsrow >> 2) & 3) * 8 + ((ldsrow >> 5) << 2) + (ldsrow & 3);
        kp[j] = Kf + ((size_t)bh * T_ + it0 * 64 + kperm) * D_ + scol;
        vp[j] = Vt + ((size_t)bh * D_ + ldsrow) * T_ + it0 * 64 + scol;
    }

    #pragma unroll
    for (int j = 0; j < 2; ++j) {
        ushort_t* dK = lds + (w * 2 + j) * 512;
        async16(kp[j], dK);
        async16(vp[j], dK + 4096);
        kp[j] += 64 * D_;
        vp[j] += 64;
    }
    __syncthreads();

    int cur = 0;
    for (int it = it0; it < it1; ++it) {
        int k0 = it * 64;
        int nxt = cur ^ 1;
        if (it + 1 < it1) {
            #pragma unroll
            for (int j = 0; j < 2; ++j) {
                ushort_t* dK = lds + nxt * 8192 + (w * 2 + j) * 512;
                async16(kp[j], dK);
                async16(vp[j], dK + 4096);
                kp[j] += 64 * D_;
                vp[j] += 64;
            }
        }

        if (k0 <= q0 + w * 32 + 31) {
            const char* KHc = (const char*)(lds + cur * 8192);
            const char* VSc = KHc + 8192;
            f16x8 pa[2][2];
            f32x4 sa[2][4];
            #pragma unroll
            for (int qs = 0; qs < 2; ++qs)
                #pragma unroll
                for (int i = 0; i < 4; ++i) sa[qs][i] = f32x4{0.f, 0.f, 0.f, 0.f};

            __builtin_amdgcn_s_setprio(1);
            #pragma unroll
            for (int kt = 0; kt < 4; ++kt) {
                int krow = kt * 16 + l15;
                int swz = (krow & 7) << 4;
                #pragma unroll
                for (int dh = 0; dh < 2; ++dh) {
                    f16x8 kf = *reinterpret_cast<const f16x8*>(KHc + krow * 128 + ((dh * 64 + l4 * 16) ^ swz));
                    sa[0][kt] = __builtin_amdgcn_mfma_f32_16x16x32_f16(kf, qf[0][dh], sa[0][kt], 0, 0, 0);
                    sa[1][kt] = __builtin_amdgcn_mfma_f32_16x16x32_f16(kf, qf[1][dh], sa[1][kt], 0, 0, 0);
                }
            }
            __builtin_amdgcn_s_setprio(0);

            int kml = k0 + l4 * 8;                   // permuted key base for this lane
            #pragma unroll
            for (int qs = 0; qs < 2; ++qs) {
                if (it >= 2 * qt) {                  // causal mask (permuted key index)
                    int qg = q0 + w * 32 + qs * 16 + l15;
                    #pragma unroll
                    for (int kt = 0; kt < 4; ++kt)
                        #pragma unroll
                        for (int r = 0; r < 4; ++r) {
                            int kact = kml + ((kt & 1) << 5) + ((kt >> 1) << 2) + r;
                            if (kact > qg) sa[qs][kt][r] = -INFINITY;
                        }
                }

                float mx = sa[qs][0][0];
                #pragma unroll
                for (int kt = 0; kt < 4; ++kt)
                    #pragma unroll
                    for (int r = 0; r < 4; ++r) mx = fmaxf(mx, sa[qs][kt][r]);
                mx = fmaxf(mx, __shfl_xor(mx, 16));
                mx = fmaxf(mx, __shfl_xor(mx, 32));

                float mn;
                if (__all(mx <= m_run[qs] + 8.0f)) {
                    mn = m_run[qs];
                } else {
                    mn = fmaxf(m_run[qs], mx);
                    float sc = exp2f(m_run[qs] - mn);
                    m_run[qs] = mn;
                    l_run[qs] *= sc;
                    #pragma unroll
                    for (int dt = 0; dt < 4; ++dt) yacc[qs][dt] *= sc;
                }

                float p[4][4];
                float rs = 0.f;
                #pragma unroll
                for (int kt = 0; kt < 4; ++kt)
                    #pragma unroll
                    for (int r = 0; r < 4; ++r) {
                        p[kt][r] = exp2f(sa[qs][kt][r] - mn);
                        rs += p[kt][r];
                    }
                l_run[qs] += rs;

                // pa built fully in-register: kt 0,2 -> keys l4*8..+7; kt 1,3 -> +32
                union { uint4 u; f16x8 hh8; } c0, c1;
                c0.u.x = pk_f16(p[0][0], p[0][1]);
                c0.u.y = pk_f16(p[0][2], p[0][3]);
                c0.u.z = pk_f16(p[2][0], p[2][1]);
                c0.u.w = pk_f16(p[2][2], p[2][3]);
                c1.u.x = pk_f16(p[1][0], p[1][1]);
                c1.u.y = pk_f16(p[1][2], p[1][3]);
                c1.u.z = pk_f16(p[3][0], p[3][1]);
                c1.u.w = pk_f16(p[3][2], p[3][3]);
                pa[qs][0] = c0.hh8;
                pa[qs][1] = c1.hh8;
            }

            __builtin_amdgcn_s_setprio(1);
            #pragma unroll
            for (int dt = 0; dt < 4; ++dt) {
                int vrow = dt * 16 + l15;
                int vswz = (vrow & 7) << 4;
                #pragma unroll
                for (int kk = 0; kk < 2; ++kk) {
                    f16x8 vf = *reinterpret_cast<const f16x8*>(VSc + vrow * 128 + ((kk * 64 + l4 * 16) ^ vswz));
                    yacc[0][dt] = __builtin_amdgcn_mfma_f32_16x16x32_f16(vf, pa[0][kk], yacc[0][dt], 0, 0, 0);
                    yacc[1][dt] = __builtin_amdgcn_mfma_f32_16x16x32_f16(vf, pa[1][kk], yacc[1][dt], 0, 0, 0);
                }
            }
            __builtin_amdgcn_s_setprio(0);
        }
        __syncthreads();
        cur = nxt;
    }

    #pragma unroll
    for (int qs = 0; qs < 2; ++qs) {
        l_run[qs] += __shfl_xor(l_run[qs], 16);
        l_run[qs] += __shfl_xor(l_run[qs], 32);
    }

    bool split = (qt >= 4);
    size_t item = split ? (((size_t)bh * 12 + (qt - 4)) * 4 + ch) : 0;
    if (split && l4 == 0) {
        float* mlp = ML + item * 256;
        #pragma unroll
        for (int qs = 0; qs < 2; ++qs) {
            int ql = w * 32 + qs * 16 + l15;
            mlp[ql] = m_run[qs];
            mlp[128 + ql] = l_run[qs];
        }
    }

    // epilogue: transpose Y'[d][q] -> [q][d] via XOR-swizzled [128][64] f32 (32 KB).
    // Both paths store NORMALIZED rows (y = O'/l); split path stores fp16.
    char* otB = smem;
    #pragma unroll
    for (int qs = 0; qs < 2; ++qs) {
        float inv = (l_run[qs] > 0.f) ? (1.0f / l_run[qs]) : 0.f;
        int rq = w * 32 + qs * 16 + l15;
        int swz = (rq & 15) << 4;
        #pragma unroll
        for (int dt = 0; dt < 4; ++dt) {
            float4 v4;
            v4.x = yacc[qs][dt][0] * inv;
            v4.y = yacc[qs][dt][1] * inv;
            v4.z = yacc[qs][dt][2] * inv;
            v4.w = yacc[qs][dt][3] * inv;
            *reinterpret_cast<float4*>(otB + rq * 256 + ((dt * 64 + l4 * 16) ^ swz)) = v4;
        }
    }
    __syncthreads();
    {
        int rr = tid >> 1, cb = (tid & 1) * 128;   // 2 threads/row, 128B halves
        int swz = (rr & 15) << 4;
        if (!split) {
            size_t ob = ((size_t)(b * T_ + q0 + rr)) * C_ + h * D_ + (tid & 1) * 32;
            #pragma unroll
            for (int u = 0; u < 8; ++u) {
                float4 v = *reinterpret_cast<const float4*>(otB + rr * 256 + ((cb + u * 16) ^ swz));
                *reinterpret_cast<float4*>(&out[ob + u * 4]) = v;
            }
        } else {
            ushort_t* dst = Oph + item * 8192 + rr * 64 + (tid & 1) * 32;
            #pragma unroll
            for (int u = 0; u < 8; ++u) {
                float4 v = *reinterpret_cast<const float4*>(otB + rr * 256 + ((cb + u * 16) ^ swz));
                uint2 pk;
                pk.x = pk_f16(v.x, v.y);
                pk.y = pk_f16(v.z, v.w);
                *reinterpret_cast<uint2*>(&dst[u * 4]) = pk;
            }
        }
    }
}

// ---------------- Kernel 3: N-way flash-combine merge (fp16 normalized partials) ----------
__global__ __launch_bounds__(256) void merge(const ushort_t* __restrict__ Oph,
                                             const float* __restrict__ ML,
                                             float* __restrict__ out)
{
    int gid = blockIdx.x * 256 + threadIdx.x;   // 48*12*128 rows x 16 float4
    int row = gid >> 4, seg = gid & 15;
    int q = row & 127, qtm = (row >> 7) % 12, bh = row / 1536;
    int qt = qtm + 4;
    int nc = (2 * qt + 9) >> 3;                 // 2,3,4

    size_t ibase = ((size_t)bh * 12 + qtm) * 4;
    float mm[4], ll[4];
    float ms = -INFINITY;
    #pragma unroll
    for (int c = 0; c < 4; ++c) {
        if (c < nc) {
            mm[c] = ML[(ibase + c) * 256 + q];
            ll[c] = ML[(ibase + c) * 256 + 128 + q];
            ms = fmaxf(ms, mm[c]);
        }
    }
    float wsum = 0.f, wt[4];
    #pragma unroll
    for (int c = 0; c < 4; ++c) {
        wt[c] = (c < nc) ? exp2f(mm[c] - ms) * ll[c] : 0.f;
        wsum += wt[c];
    }
    float inv = 1.0f / wsum;

    float4 r = {0.f, 0.f, 0.f, 0.f};
    #pragma unroll
    for (int c = 0; c < 4; ++c) {
        if (c < nc) {
            float wc = wt[c] * inv;
            f16x4v o = *reinterpret_cast<const f16x4v*>(&Oph[(ibase + c) * 8192 + q * 64 + seg * 4]);
            r.x += (float)o[0] * wc;
            r.y += (float)o[1] * wc;
            r.z += (float)o[2] * wc;
            r.w += (float)o[3] * wc;
        }
    }

    int b = bh / H_, h = bh % H_;
    int t = qt * 128 + q;
    *reinterpret_cast<float4*>(&out[((size_t)(b * T_ + t)) * C_ + h * D_ + seg * 4]) = r;
}

extern "C" void kernel_launch(void* const* d_in, const int* in_sizes, int n_in,
                              void* d_out, int out_size, void* d_ws, size_t ws_size,
                              hipStream_t stream)
{
    const float* x    = (const float*)d_in[0];
    const float* W    = (const float*)d_in[1];
    const float* bias = (const float*)d_in[2];

    const size_t per = (size_t)BH_ * T_ * D_;       // 6291456
    _Float16* Qf = (_Float16*)d_ws;
    _Float16* Kf = Qf + per;
    _Float16* Vt = Kf + per;
    _Float16* Xh = Vt + per;                        // 8192*768
    _Float16* Wh = Xh + (size_t)8192 * C_;          // 2304*768
    ushort_t* Oph = (ushort_t*)(Wh + (size_t)N3C * C_);   // 48*12*4*8192 fp16 = 37.7 MB
    float*    ML  = (float*)(Oph + (size_t)48 * 12 * 4 * 8192);  // 48*12*4*256 f32

    conv_xw<<<dim3(3072 + 432), 256, 0, stream>>>(x, W, Xh, Wh);
    qkv_gemm<<<dim3(64 * 18), 256, 0, stream>>>(Xh, Wh, bias, Qf, Kf, Vt);
    attn<<<dim3(40 * BH_), 256, 0, stream>>>(Qf, Kf, Vt, (float*)d_out, Oph, ML);
    merge<<<dim3(48 * 12 * 128 * 16 / 256), 256, 0, stream>>>(Oph, ML, (float*)d_out);
}

// Round 20
// 126.963 us; speedup vs baseline: 1.0575x; 1.0575x over previous
//
#include <hip/hip_runtime.h>
#include <math.h>

#define B_ 4
#define T_ 2048
#define C_ 768
#define H_ 12
#define D_ 64
#define N3C (3*C_)
#define BH_ (B_*H_)
#define QSCALE 11.5415603f   // 8 * log2(e): fold sqrt(d) and exp->exp2 into Q

typedef float f32x4 __attribute__((ext_vector_type(4)));
typedef _Float16 f16x8 __attribute__((ext_vector_type(8)));
typedef _Float16 f16x4v __attribute__((ext_vector_type(4)));
typedef unsigned short ushort_t;

__device__ __forceinline__ void async16(const void* g, void* l) {
    __builtin_amdgcn_global_load_lds(
        (const __attribute__((address_space(1))) unsigned int*)(g),
        (__attribute__((address_space(3))) unsigned int*)(l),
        16, 0, 0);
}

__device__ __forceinline__ unsigned pk_f16(float a, float b) {
    __fp16 r2[2];
    *(__fp16 __attribute__((ext_vector_type(2)))*)r2 = __builtin_amdgcn_cvt_pkrtz(a, b);
    return *(unsigned*)r2;
}

// ---------------- Kernel 0: fused Xh = fp16(x) + Wh[n][k] = fp16(W[k][n]) ----------------
__global__ __launch_bounds__(256) void conv_xw(const float* __restrict__ x,
                                               const float* __restrict__ W,
                                               _Float16* __restrict__ Xh,
                                               _Float16* __restrict__ Wh)
{
    __shared__ float tile[64][65];
    int bid = blockIdx.x;
    int tid = threadIdx.x;
    if (bid < 3072) {                                // x conversion: 8192*768/8 octs
        int idx = bid * 256 + tid;
        const float4 a = *reinterpret_cast<const float4*>(&x[(size_t)idx * 8]);
        const float4 b = *reinterpret_cast<const float4*>(&x[(size_t)idx * 8 + 4]);
        f16x8 o = {(_Float16)a.x, (_Float16)a.y, (_Float16)a.z, (_Float16)a.w,
                   (_Float16)b.x, (_Float16)b.y, (_Float16)b.z, (_Float16)b.w};
        *reinterpret_cast<f16x8*>(&Xh[(size_t)idx * 8]) = o;
    } else {                                         // W transpose+convert
        int b2 = bid - 3072;
        int n0 = (b2 % 36) * 64, k0 = (b2 / 36) * 64;
        #pragma unroll
        for (int t = 0; t < 16; ++t) {
            int c = t * 256 + tid;
            int kr = c >> 6, nc = c & 63;
            tile[kr][nc] = W[(size_t)(k0 + kr) * N3C + n0 + nc];
        }
        __syncthreads();
        #pragma unroll
        for (int t = 0; t < 16; ++t) {
            int c = t * 256 + tid;
            int nr = c >> 6, kc = c & 63;
            Wh[(size_t)(n0 + nr) * C_ + k0 + kc] = (_Float16)tile[kc][nr];
        }
    }
}

// ---------------- Kernel 1: qkv GEMM, fp16 MFMA, K=768 (2-phase dbuf) ----------------
__global__ __launch_bounds__(256) void qkv_gemm(const _Float16* __restrict__ Xh,
                                                const _Float16* __restrict__ Wh,
                                                const float* __restrict__ bias,
                                                _Float16* __restrict__ Qf,
                                                _Float16* __restrict__ Kf,
                                                _Float16* __restrict__ Vt)
{
    __shared__ __align__(16) ushort_t SMEM[2 * 2 * 128 * 64];   // 64 KB

    int tid = threadIdx.x, lane = tid & 63, w = tid >> 6;
    int wm = w >> 1, wn = w & 1;
    int l15 = lane & 15, l4 = lane >> 4;
    int srow = lane >> 3;
    int scol = (((lane & 7) ^ srow)) << 3;

    int wg = blockIdx.x;
    int l = (wg & 7) * 144 + (wg >> 3);
    int mt = l / 18, nt = l % 18;
    int row0 = mt * 128, col0 = nt * 128;

    f32x4 acc[4][4];
    #pragma unroll
    for (int i = 0; i < 4; ++i)
        #pragma unroll
        for (int j = 0; j < 4; ++j)
            acc[i][j] = f32x4{0.f, 0.f, 0.f, 0.f};

    #pragma unroll
    for (int j = 0; j < 4; ++j) {
        int rowb = w * 32 + j * 8;
        async16(Xh + (size_t)(row0 + rowb + srow) * C_ + scol, &SMEM[rowb * 64]);
        async16(Wh + (size_t)(col0 + rowb + srow) * C_ + scol, &SMEM[8192 + rowb * 64]);
    }
    __syncthreads();

    int cur = 0;
    for (int it = 0; it < 12; ++it) {
        int nxt = cur ^ 1;
        int k0n = (it + 1) * 64;
        bool pf = (it + 1 < 12);
        const char* AsC = (const char*)(SMEM + cur * 16384);
        const char* BsC = AsC + 16384;
        ushort_t* An = SMEM + nxt * 16384;
        ushort_t* Bn = An + 8192;

        if (pf) {
            #pragma unroll
            for (int j = 0; j < 2; ++j) {
                int rowb = w * 32 + j * 8;
                async16(Xh + (size_t)(row0 + rowb + srow) * C_ + k0n + scol, &An[rowb * 64]);
                async16(Wh + (size_t)(col0 + rowb + srow) * C_ + k0n + scol, &Bn[rowb * 64]);
            }
        }
        f16x8 bfr[4][2];
        #pragma unroll
        for (int n = 0; n < 4; ++n) {
            int r = wn * 64 + n * 16 + l15;
            #pragma unroll
            for (int kk = 0; kk < 2; ++kk)
                bfr[n][kk] = *reinterpret_cast<const f16x8*>(BsC + r * 128 + ((kk * 64 + l4 * 16) ^ ((r & 7) << 4)));
        }
        {
            f16x8 af[2][2];
            #pragma unroll
            for (int m = 0; m < 2; ++m) {
                int r = wm * 64 + m * 16 + l15;
                #pragma unroll
                for (int kk = 0; kk < 2; ++kk)
                    af[m][kk] = *reinterpret_cast<const f16x8*>(AsC + r * 128 + ((kk * 64 + l4 * 16) ^ ((r & 7) << 4)));
            }
            #pragma unroll
            for (int kk = 0; kk < 2; ++kk)
                #pragma unroll
                for (int m = 0; m < 2; ++m)
                    #pragma unroll
                    for (int n = 0; n < 4; ++n)
                        acc[m][n] = __builtin_amdgcn_mfma_f32_16x16x32_f16(af[m][kk], bfr[n][kk], acc[m][n], 0, 0, 0);
        }

        if (pf) {
            #pragma unroll
            for (int j = 2; j < 4; ++j) {
                int rowb = w * 32 + j * 8;
                async16(Xh + (size_t)(row0 + rowb + srow) * C_ + k0n + scol, &An[rowb * 64]);
                async16(Wh + (size_t)(col0 + rowb + srow) * C_ + k0n + scol, &Bn[rowb * 64]);
            }
        }
        {
            f16x8 af[2][2];
            #pragma unroll
            for (int m = 0; m < 2; ++m) {
                int r = wm * 64 + (m + 2) * 16 + l15;
                #pragma unroll
                for (int kk = 0; kk < 2; ++kk)
                    af[m][kk] = *reinterpret_cast<const f16x8*>(AsC + r * 128 + ((kk * 64 + l4 * 16) ^ ((r & 7) << 4)));
            }
            #pragma unroll
            for (int kk = 0; kk < 2; ++kk)
                #pragma unroll
                for (int m = 0; m < 2; ++m)
                    #pragma unroll
                    for (int n = 0; n < 4; ++n)
                        acc[m + 2][n] = __builtin_amdgcn_mfma_f32_16x16x32_f16(af[m][kk], bfr[n][kk], acc[m + 2][n], 0, 0, 0);
        }

        __syncthreads();
        cur = nxt;
    }

    // epilogue: stage fp16 tile in LDS, coalesced 16B stores
    char* EB = (char*)SMEM;
    int p = col0 / C_;

    if (p < 2) {
        #pragma unroll
        for (int n = 0; n < 4; ++n) {
            int col = wn * 64 + n * 16 + l15;
            float bv = bias[col0 + col];
            #pragma unroll
            for (int m = 0; m < 4; ++m) {
                #pragma unroll
                for (int r = 0; r < 4; ++r) {
                    int row = wm * 64 + m * 16 + l4 * 4 + r;
                    float v = acc[m][n][r] + bv;
                    if (p == 0) v *= QSCALE;
                    int off = row * 256 + ((col * 2) ^ ((row & 7) << 4));
                    *reinterpret_cast<_Float16*>(EB + off) = (_Float16)v;
                }
            }
        }
        __syncthreads();
        int ti = tid >> 1, half = tid & 1;
        int grow = row0 + ti;
        int bq = grow >> 11, t = grow & (T_ - 1);
        int rem = (col0 + half * 64) - p * C_;
        int hh = rem >> 6;
        _Float16* dst = (p == 0 ? Qf : Kf) + ((size_t)(bq * H_ + hh) * T_ + t) * D_;
        #pragma unroll
        for (int u = 0; u < 8; ++u) {
            int off = ti * 256 + ((half * 128 + u * 16) ^ ((ti & 7) << 4));
            *reinterpret_cast<uint4*>((char*)dst + u * 16) = *reinterpret_cast<const uint4*>(EB + off);
        }
    } else {
        #pragma unroll
        for (int n = 0; n < 4; ++n) {
            int col = wn * 64 + n * 16 + l15;
            float bv = bias[col0 + col];
            #pragma unroll
            for (int m = 0; m < 4; ++m) {
                int row = wm * 64 + m * 16 + l4 * 4;
                uint2 pk;
                pk.x = pk_f16(acc[m][n][0] + bv, acc[m][n][1] + bv);
                pk.y = pk_f16(acc[m][n][2] + bv, acc[m][n][3] + bv);
                int off = col * 256 + ((row * 2) ^ ((col & 15) << 4));
                *reinterpret_cast<uint2*>(EB + off) = pk;
            }
        }
        __syncthreads();
        int dcol = tid >> 1, half = tid & 1;
        int rem = (col0 + dcol) - 1536;
        int hh = rem >> 6, dd = rem & 63;
        int bq = row0 >> 11, t0 = row0 & (T_ - 1);
        _Float16* dst = Vt + ((size_t)(bq * H_ + hh) * D_ + dd) * T_ + t0 + half * 64;
        #pragma unroll
        for (int u = 0; u < 8; ++u) {
            int off = dcol * 256 + ((half * 128 + u * 16) ^ ((dcol & 15) << 4));
            *reinterpret_cast<uint4*>((char*)dst + u * 16) = *reinterpret_cast<const uint4*>(EB + off);
        }
    }
}

// ---------------- Kernel 2: flash attention, permuted-K staging (R16/R18 best) ------------
__device__ const unsigned char ITEM_QT[24] = {15,15,7,14,14,13,13,6,12,12,11,11,5,10,10,9,9,4,8,8,3,2,1,0};
__device__ const unsigned char ITEM_CH[24] = { 0, 1,0, 0, 1, 0, 1,0, 0, 1, 0, 1,0, 0, 1,0,1,0,0,1,0,0,0,0};

__global__ __launch_bounds__(256, 4) void attn(const _Float16* __restrict__ Qf,
                                               const _Float16* __restrict__ Kf,
                                               const _Float16* __restrict__ Vt,
                                               float* __restrict__ out,
                                               ushort_t* __restrict__ Oph,
                                               float* __restrict__ ML)
{
    // shorts layout: buf0 K[4096] V[4096] | buf1 K V  = 32768 B
    __shared__ __align__(16) char smem[32768];
    ushort_t* lds = (ushort_t*)smem;

    int tid = threadIdx.x, lane = tid & 63, w = tid >> 6;
    int l15 = lane & 15, l4 = lane >> 4;
    int bid = blockIdx.x;
    int rank = bid / BH_;
    int bh = bid % BH_;
    int qt = ITEM_QT[rank];
    int ch = ITEM_CH[rank];
    int b = bh / H_, h = bh % H_;
    int q0 = qt * 128;

    int it0 = (qt < 8 || ch == 0) ? 0 : (qt + 1);
    int it1 = (qt >= 8 && ch == 0) ? (qt + 1) : (2 * qt + 2);

    f16x8 qf[2][2];
    #pragma unroll
    for (int qs = 0; qs < 2; ++qs) {
        int q = q0 + w * 32 + qs * 16 + l15;
        const _Float16* ph = Qf + ((size_t)bh * T_ + q) * D_;
        qf[qs][0] = *reinterpret_cast<const f16x8*>(ph + l4 * 8);
        qf[qs][1] = *reinterpret_cast<const f16x8*>(ph + 32 + l4 * 8);
    }

    f32x4 yacc[2][4];
    #pragma unroll
    for (int qs = 0; qs < 2; ++qs)
        #pragma unroll
        for (int dt = 0; dt < 4; ++dt)
            yacc[qs][dt] = f32x4{0.f, 0.f, 0.f, 0.f};
    float m_run[2] = {-INFINITY, -INFINITY};
    float l_run[2] = {0.f, 0.f};          // per-lane PARTIAL (reduced at epilogue)

    int srow = lane >> 3;
    int scol = ((lane & 7) ^ srow) << 3;

    const _Float16* kp[2];
    const _Float16* vp[2];
    #pragma unroll
    for (int j = 0; j < 2; ++j) {
        int ldsrow = (w * 2 + j) * 8 + srow;
        // kappa: LDS row -> global key offset (bijective on [0,64))
        int kperm = ((ldsrow >> 4) & 1) * 32 + ((ldsrow >> 2) & 3) * 8 + ((ldsrow >> 5) << 2) + (ldsrow & 3);
        kp[j] = Kf + ((size_t)bh * T_ + it0 * 64 + kperm) * D_ + scol;
        vp[j] = Vt + ((size_t)bh * D_ + ldsrow) * T_ + it0 * 64 + scol;
    }

    #pragma unroll
    for (int j = 0; j < 2; ++j) {
        ushort_t* dK = lds + (w * 2 + j) * 512;
        async16(kp[j], dK);
        async16(vp[j], dK + 4096);
        kp[j] += 64 * D_;
        vp[j] += 64;
    }
    __syncthreads();

    int cur = 0;
    for (int it = it0; it < it1; ++it) {
        int k0 = it * 64;
        int nxt = cur ^ 1;
        if (it + 1 < it1) {
            #pragma unroll
            for (int j = 0; j < 2; ++j) {
                ushort_t* dK = lds + nxt * 8192 + (w * 2 + j) * 512;
                async16(kp[j], dK);
                async16(vp[j], dK + 4096);
                kp[j] += 64 * D_;
                vp[j] += 64;
            }
        }

        if (k0 <= q0 + w * 32 + 31) {
            const char* KHc = (const char*)(lds + cur * 8192);
            const char* VSc = KHc + 8192;
            f16x8 pa[2][2];
            f32x4 sa[2][4];
            #pragma unroll
            for (int qs = 0; qs < 2; ++qs)
                #pragma unroll
                for (int i = 0; i < 4; ++i) sa[qs][i] = f32x4{0.f, 0.f, 0.f, 0.f};

            __builtin_amdgcn_s_setprio(1);
            #pragma unroll
            for (int kt = 0; kt < 4; ++kt) {
                int krow = kt * 16 + l15;
                int swz = (krow & 7) << 4;
                #pragma unroll
                for (int dh = 0; dh < 2; ++dh) {
                    f16x8 kf = *reinterpret_cast<const f16x8*>(KHc + krow * 128 + ((dh * 64 + l4 * 16) ^ swz));
                    sa[0][kt] = __builtin_amdgcn_mfma_f32_16x16x32_f16(kf, qf[0][dh], sa[0][kt], 0, 0, 0);
                    sa[1][kt] = __builtin_amdgcn_mfma_f32_16x16x32_f16(kf, qf[1][dh], sa[1][kt], 0, 0, 0);
                }
            }
            __builtin_amdgcn_s_setprio(0);

            int kml = k0 + l4 * 8;                   // permuted key base for this lane
            #pragma unroll
            for (int qs = 0; qs < 2; ++qs) {
                if (it >= 2 * qt) {                  // causal mask (permuted key index)
                    int qg = q0 + w * 32 + qs * 16 + l15;
                    #pragma unroll
                    for (int kt = 0; kt < 4; ++kt)
                        #pragma unroll
                        for (int r = 0; r < 4; ++r) {
                            int kact = kml + ((kt & 1) << 5) + ((kt >> 1) << 2) + r;
                            if (kact > qg) sa[qs][kt][r] = -INFINITY;
                        }
                }

                float mx = sa[qs][0][0];
                #pragma unroll
                for (int kt = 0; kt < 4; ++kt)
                    #pragma unroll
                    for (int r = 0; r < 4; ++r) mx = fmaxf(mx, sa[qs][kt][r]);
                mx = fmaxf(mx, __shfl_xor(mx, 16));
                mx = fmaxf(mx, __shfl_xor(mx, 32));

                float mn;
                if (__all(mx <= m_run[qs] + 8.0f)) {
                    mn = m_run[qs];
                } else {
                    mn = fmaxf(m_run[qs], mx);
                    float sc = exp2f(m_run[qs] - mn);
                    m_run[qs] = mn;
                    l_run[qs] *= sc;
                    #pragma unroll
                    for (int dt = 0; dt < 4; ++dt) yacc[qs][dt] *= sc;
                }

                float p[4][4];
                float rs = 0.f;
                #pragma unroll
                for (int kt = 0; kt < 4; ++kt)
                    #pragma unroll
                    for (int r = 0; r < 4; ++r) {
                        p[kt][r] = exp2f(sa[qs][kt][r] - mn);
                        rs += p[kt][r];
                    }
                l_run[qs] += rs;

                // pa built fully in-register: kt 0,2 -> keys l4*8..+7; kt 1,3 -> +32
                union { uint4 u; f16x8 hh8; } c0, c1;
                c0.u.x = pk_f16(p[0][0], p[0][1]);
                c0.u.y = pk_f16(p[0][2], p[0][3]);
                c0.u.z = pk_f16(p[2][0], p[2][1]);
                c0.u.w = pk_f16(p[2][2], p[2][3]);
                c1.u.x = pk_f16(p[1][0], p[1][1]);
                c1.u.y = pk_f16(p[1][2], p[1][3]);
                c1.u.z = pk_f16(p[3][0], p[3][1]);
                c1.u.w = pk_f16(p[3][2], p[3][3]);
                pa[qs][0] = c0.hh8;
                pa[qs][1] = c1.hh8;
            }

            __builtin_amdgcn_s_setprio(1);
            #pragma unroll
            for (int dt = 0; dt < 4; ++dt) {
                int vrow = dt * 16 + l15;
                int vswz = (vrow & 7) << 4;
                #pragma unroll
                for (int kk = 0; kk < 2; ++kk) {
                    f16x8 vf = *reinterpret_cast<const f16x8*>(VSc + vrow * 128 + ((kk * 64 + l4 * 16) ^ vswz));
                    yacc[0][dt] = __builtin_amdgcn_mfma_f32_16x16x32_f16(vf, pa[0][kk], yacc[0][dt], 0, 0, 0);
                    yacc[1][dt] = __builtin_amdgcn_mfma_f32_16x16x32_f16(vf, pa[1][kk], yacc[1][dt], 0, 0, 0);
                }
            }
            __builtin_amdgcn_s_setprio(0);
        }
        __syncthreads();
        cur = nxt;
    }

    #pragma unroll
    for (int qs = 0; qs < 2; ++qs) {
        l_run[qs] += __shfl_xor(l_run[qs], 16);
        l_run[qs] += __shfl_xor(l_run[qs], 32);
    }

    bool split = (qt >= 8);
    if (split && l4 == 0) {
        float* mlp = ML + (((size_t)bh * 8 + (qt - 8)) * 2 + ch) * 256;
        #pragma unroll
        for (int qs = 0; qs < 2; ++qs) {
            int ql = w * 32 + qs * 16 + l15;
            mlp[ql] = m_run[qs];
            mlp[128 + ql] = l_run[qs];
        }
    }

    // epilogue: transpose Y'[d][q] -> [q][d] via XOR-swizzled [128][64] f32 (32 KB).
    // Both paths store NORMALIZED rows (y = O'/l); split path stores fp16.
    char* otB = smem;
    #pragma unroll
    for (int qs = 0; qs < 2; ++qs) {
        float inv = 1.0f / l_run[qs];
        int rq = w * 32 + qs * 16 + l15;
        int swz = (rq & 15) << 4;
        #pragma unroll
        for (int dt = 0; dt < 4; ++dt) {
            float4 v4;
            v4.x = yacc[qs][dt][0] * inv;
            v4.y = yacc[qs][dt][1] * inv;
            v4.z = yacc[qs][dt][2] * inv;
            v4.w = yacc[qs][dt][3] * inv;
            *reinterpret_cast<float4*>(otB + rq * 256 + ((dt * 64 + l4 * 16) ^ swz)) = v4;
        }
    }
    __syncthreads();
    {
        int rr = tid >> 1, cb = (tid & 1) * 128;   // 2 threads/row, 128B halves
        int swz = (rr & 15) << 4;
        if (!split) {
            size_t ob = ((size_t)(b * T_ + q0 + rr)) * C_ + h * D_ + (tid & 1) * 32;
            #pragma unroll
            for (int u = 0; u < 8; ++u) {
                float4 v = *reinterpret_cast<const float4*>(otB + rr * 256 + ((cb + u * 16) ^ swz));
                *reinterpret_cast<float4*>(&out[ob + u * 4]) = v;
            }
        } else {
            ushort_t* dst = Oph + (((size_t)bh * 8 + (qt - 8)) * 2 + ch) * 8192 + rr * 64 + (tid & 1) * 32;
            #pragma unroll
            for (int u = 0; u < 8; ++u) {
                float4 v = *reinterpret_cast<const float4*>(otB + rr * 256 + ((cb + u * 16) ^ swz));
                uint2 pk;
                pk.x = pk_f16(v.x, v.y);
                pk.y = pk_f16(v.z, v.w);
                *reinterpret_cast<uint2*>(&dst[u * 4]) = pk;
            }
        }
    }
}

// ---------------- Kernel 3: flash-combine merge (fp16 normalized partials) ----------------
__global__ __launch_bounds__(256) void merge(const ushort_t* __restrict__ Oph,
                                             const float* __restrict__ ML,
                                             float* __restrict__ out)
{
    int gid = blockIdx.x * 256 + threadIdx.x;   // 49152 rows x 16 float4
    int row = gid >> 4, seg = gid & 15;
    int q = row & 127, qt8 = (row >> 7) & 7, bh = row >> 10;

    size_t mbase = ((size_t)bh * 8 + qt8) * 2 * 256;
    float m1 = ML[mbase + q],       l1 = ML[mbase + 128 + q];
    float m2 = ML[mbase + 256 + q], l2 = ML[mbase + 256 + 128 + q];
    float m = fmaxf(m1, m2);
    float w1 = exp2f(m1 - m) * l1, w2 = exp2f(m2 - m) * l2;
    float inv = 1.0f / (w1 + w2);
    w1 *= inv; w2 *= inv;

    size_t obase = ((size_t)bh * 8 + qt8) * 2 * 8192 + q * 64 + seg * 4;
    f16x4v o1 = *reinterpret_cast<const f16x4v*>(&Oph[obase]);
    f16x4v o2 = *reinterpret_cast<const f16x4v*>(&Oph[obase + 8192]);
    float4 r;
    r.x = (float)o1[0] * w1 + (float)o2[0] * w2;
    r.y = (float)o1[1] * w1 + (float)o2[1] * w2;
    r.z = (float)o1[2] * w1 + (float)o2[2] * w2;
    r.w = (float)o1[3] * w1 + (float)o2[3] * w2;

    int b = bh / H_, h = bh % H_;
    int t = (qt8 + 8) * 128 + q;
    *reinterpret_cast<float4*>(&out[((size_t)(b * T_ + t)) * C_ + h * D_ + seg * 4]) = r;
}

extern "C" void kernel_launch(void* const* d_in, const int* in_sizes, int n_in,
                              void* d_out, int out_size, void* d_ws, size_t ws_size,
                              hipStream_t stream)
{
    const float* x    = (const float*)d_in[0];
    const float* W    = (const float*)d_in[1];
    const float* bias = (const float*)d_in[2];

    const size_t per = (size_t)BH_ * T_ * D_;       // 6291456
    _Float16* Qf = (_Float16*)d_ws;
    _Float16* Kf = Qf + per;
    _Float16* Vt = Kf + per;
    _Float16* Xh = Vt + per;                        // 8192*768
    _Float16* Wh = Xh + (size_t)8192 * C_;          // 2304*768
    ushort_t* Oph = (ushort_t*)(Wh + (size_t)N3C * C_);   // 48*8*2*8192 fp16 = 12.6 MB
    float*    ML  = (float*)(Oph + (size_t)48 * 8 * 2 * 8192);  // 48*8*2*256 f32

    conv_xw<<<dim3(3072 + 432), 256, 0, stream>>>(x, W, Xh, Wh);
    qkv_gemm<<<dim3(64 * 18), 256, 0, stream>>>(Xh, Wh, bias, Qf, Kf, Vt);
    attn<<<dim3(24 * BH_), 256, 0, stream>>>(Qf, Kf, Vt, (float*)d_out, Oph, ML);
    merge<<<dim3(49152 * 16 / 256), 256, 0, stream>>>(Oph, ML, (float*)d_out);
}